// Round 5
// baseline (869.436 us; speedup 1.0000x reference)
//
#include <hip/hip_runtime.h>
#include <hip/hip_bf16.h>

// Problem constants
#define VV 200000
#define DD 512
#define NN 32768
#define RR 8
#define HH 16
#define CLAMPV 1000.0f

typedef __attribute__((ext_vector_type(8))) short short8;
typedef __attribute__((ext_vector_type(4))) float f32x4;
typedef __attribute__((ext_vector_type(4))) unsigned int u32x4;

__device__ __forceinline__ unsigned f2bf(float f) {
  union { float f; unsigned u; } v; v.f = f;
  return (v.u + 0x7FFFu + ((v.u >> 16) & 1u)) >> 16;   // RNE f32->bf16
}
__device__ __forceinline__ unsigned pack2(float lo, float hi) {
  return f2bf(lo) | (f2bf(hi) << 16);
}

// ---------------- prep 1: addvec[d] = clip(phase(t))[d] + err[d] -------------
__global__ void prep_phase_k(const float* __restrict__ base_phase,
                             const float* __restrict__ amp,
                             const float* __restrict__ freq,
                             const float* __restrict__ poff,
                             const float* __restrict__ err,
                             const int* __restrict__ tstep,
                             float* __restrict__ addvec) {
  const int d = threadIdx.x;          // 512 threads
  const float t = (float)(*tstep);
  float s = base_phase[d];
#pragma unroll
  for (int h = 0; h < HH; ++h)
    s += amp[h * DD + d] * sinf(freq[h] * t + poff[h]);
  s = fminf(fmaxf(s, -CLAMPV), CLAMPV);
  addvec[d] = s + err[d];
}

// ------------- prep 2: B in MFMA fragment-image layout -----------------------
// bt[((s*32 + g)*64 + l)*8 + j] = bf16( transform[k][e] * w[k/512] )
//   s = k32-slice (0..127), g = e-group (0..31), e = g*16 + (l&15),
//   k = s*32 + (l>>4)*8 + j  — the verified 16x16x32 B-fragment lane mapping.
__global__ void prep_bt_k(const float* __restrict__ transform,
                          const float* __restrict__ cw,
                          unsigned short* __restrict__ bt) {
  const int bid = blockIdx.x;                    // 1024 blocks x 256 threads
  const int s = bid >> 3;                        // 0..127
  const int g = ((bid & 7) << 2) + (threadIdx.x >> 6);  // 0..31
  const int l = threadIdx.x & 63;
  const int e = g * 16 + (l & 15);
  const int k0 = s * 32 + ((l >> 4) << 3);
  const float scale = cw[s >> 4];                // r = (s*32)/512, uniform
  u32x4 w;
#pragma unroll
  for (int p = 0; p < 4; ++p) {
    const float lo = transform[(size_t)(k0 + 2 * p) * DD + e] * scale;
    const float hi = transform[(size_t)(k0 + 2 * p + 1) * DD + e] * scale;
    w[p] = pack2(lo, hi);
  }
  *(u32x4*)(bt + (((size_t)s * 32 + g) * 64 + l) * 8) = w;
}

// ----------------------------- main fused GEMM -------------------------------
// C[32768x512] = gatherA[32768x4096] x B[4096x512] (+ base + addvec, clamp).
// BM=64, BN=512, BK=64. 512 blocks (2/CU for cross-block TLP), 8 waves,
// wave = 64x64 (4x4 frags). R3's counted-vmcnt schedule: A-gather 2 kt deep
// (reg-staged f32 -> bf16 -> LDS dbuf, R1's zero-conflict 128B-row layout),
// B fragments 1 kt deep (reg dbuf from L2-resident fragment-image ws).
// Refs preloaded to LDS (no mid-loop vmcnt(0) drain from ref loads).
#define VM_WAIT(N) asm volatile("s_waitcnt vmcnt(" #N ")" ::: "memory")
#define LGKM0()    asm volatile("s_waitcnt lgkmcnt(0)" ::: "memory")
#define BARRIER()  __builtin_amdgcn_s_barrier()

#define LOADB(DST, KTP1)                                                      \
  {                                                                           \
    const unsigned short* b0_ =                                               \
        bt + (size_t)(KTP1) * 32768 + wv * 2048 + lane * 8;                   \
    _Pragma("unroll") for (int n = 0; n < 4; ++n) {                           \
      DST[n][0] = *(const short8*)(b0_ + n * 512);                            \
      DST[n][1] = *(const short8*)(b0_ + 16384 + n * 512);                    \
    }                                                                         \
  }

#define GSTEP(KT, ASC, ASN, BFC, BFN, ABR, ABW, VMN, DOA, DOB, DOBAR)         \
  {                                                                           \
    if (DOB) LOADB(BFN, (KT) + 1);                                            \
    if (DOA) { /* A(KT+2): 8 floats/thread, 256B-contig per row */            \
      const int kt2_ = (KT) + 2;                                              \
      if ((kt2_ & 7) == 0) ridx = refs_lds[arow * 8 + (kt2_ >> 3)];           \
      const float* asrc_ =                                                    \
          codebook + (size_t)ridx * DD + ((kt2_ & 7) << 6) + ac8 * 8;         \
      ASN[0] = *(const f32x4*)(asrc_);                                        \
      ASN[1] = *(const f32x4*)(asrc_ + 4);                                    \
    }                                                                         \
    VM_WAIT(VMN); /* retires A(KT+1) + B(KT); newer stay in flight */         \
    if ((KT) < 63) { /* convert + ds_write A(KT+1) -> ABW */                  \
      u32x4 w_;                                                               \
      w_[0] = pack2(ASC[0][0], ASC[0][1]); w_[1] = pack2(ASC[0][2], ASC[0][3]);\
      w_[2] = pack2(ASC[1][0], ASC[1][1]); w_[3] = pack2(ASC[1][2], ASC[1][3]);\
      *(u32x4*)((ABW) + awb) = w_;                                            \
    }                                                                         \
    __builtin_amdgcn_s_setprio(1);                                            \
    _Pragma("unroll") for (int ks = 0; ks < 2; ++ks) {                        \
      _Pragma("unroll") for (int m = 0; m < 4; ++m) {                         \
        const short8 aFv = *(const short8*)((ABR) + m * 2048 + rbase +        \
                                            ((ks * 64 + koff) ^ rsw));        \
        _Pragma("unroll") for (int n = 0; n < 4; ++n)                         \
          acc[m][n] = __builtin_amdgcn_mfma_f32_16x16x32_bf16(                \
              aFv, (BFC)[n][ks], acc[m][n], 0, 0, 0);                         \
      }                                                                       \
    }                                                                         \
    __builtin_amdgcn_s_setprio(0);                                            \
    if (DOBAR) { LGKM0(); BARRIER(); }                                        \
  }

__global__ __launch_bounds__(512, 4)
void rw_gemm_k(const float* __restrict__ codebook,
               const int* __restrict__ base_idx,
               const int* __restrict__ ref_idx,
               const unsigned short* __restrict__ bt,
               const float* __restrict__ addvec,
               float* __restrict__ out) {
  __shared__ unsigned short aT[2][64 * 64];      // 8 KB x2, swizzled [row][k64]
  __shared__ int refs_lds[512];                  // 64 rows x 8 refs

  const int tid = threadIdx.x;
  const int lane = tid & 63;
  const int wv = tid >> 6;                       // 0..7 -> col block (64 cols)
  const int mb = blockIdx.x;                     // rows mb*64 .. +63

  const f32x4 zero = {0.f, 0.f, 0.f, 0.f};
  f32x4 acc[4][4];
#pragma unroll
  for (int m = 0; m < 4; ++m)
#pragma unroll
    for (int n = 0; n < 4; ++n)
      acc[m][n] = zero;

  // A staging map (R1 zero-conflict): row = tid/8, 8 floats at chunk tid%8
  const int arow = tid >> 3;
  const int ac8 = tid & 7;
  const int awb = arow * 128 + ((ac8 * 16) ^ ((arow & 7) << 4));
  char* ab0 = (char*)&aT[0][0];
  char* ab1 = (char*)&aT[1][0];

  // fragment-read constants (R1 zero-conflict): row = m*16 + (lane&15)
  const int rsw = (lane & 7) << 4;
  const int rbase = (lane & 15) * 128;
  const int koff = (lane >> 4) * 16;

  short8 bF0[4][2], bF1[4][2];
  f32x4 as0[2], as1[2];

  // ---- prologue: refs -> LDS, A(0)->buf0, B(0)->bF0, A(1)->as1 ----
  refs_lds[tid] = ref_idx[(size_t)mb * 512 + tid];   // coalesced 2KB
  __syncthreads();
  int ridx = refs_lds[arow * 8];

  {
    const float* a0s = codebook + (size_t)ridx * DD + ac8 * 8;
    f32x4 p0 = *(const f32x4*)(a0s);
    f32x4 p1 = *(const f32x4*)(a0s + 4);
    LOADB(bF0, 0);
    const float* a1s = codebook + (size_t)ridx * DD + 64 + ac8 * 8;  // kt=1
    as1[0] = *(const f32x4*)(a1s);
    as1[1] = *(const f32x4*)(a1s + 4);
    VM_WAIT(10);                                 // A(0) retired; 10 in flight
    u32x4 w_;
    w_[0] = pack2(p0[0], p0[1]); w_[1] = pack2(p0[2], p0[3]);
    w_[2] = pack2(p1[0], p1[1]); w_[3] = pack2(p1[2], p1[3]);
    *(u32x4*)(ab0 + awb) = w_;
    LGKM0(); BARRIER();
  }

  // ---- main pipeline: kt = 0..61 steady, 62/63 tail ----
  for (int k2 = 0; k2 < 31; ++k2) {
    const int kt = k2 * 2;
    GSTEP(kt,     as1, as0, bF0, bF1, ab0, ab1, 10, 1, 1, 1);
    GSTEP(kt + 1, as0, as1, bF1, bF0, ab1, ab0, 10, 1, 1, 1);
  }
  GSTEP(62, as1, as0, bF0, bF1, ab0, ab1, 8, 0, 1, 1);
  GSTEP(63, as0, as1, bF1, bF0, ab1, ab0, 0, 0, 0, 0);

  // epilogue: + base gather + addvec, clamp, store f32
  // C/D layout: col = lane&15, row = (lane>>4)*4 + reg
#pragma unroll
  for (int m = 0; m < 4; ++m) {
#pragma unroll
    for (int j = 0; j < 4; ++j) {
      const int row = mb * 64 + m * 16 + ((lane >> 4) << 2) + j;
      const int bi = base_idx[row];
      const float* brow = codebook + (size_t)bi * DD;
#pragma unroll
      for (int n = 0; n < 4; ++n) {
        const int col = wv * 64 + n * 16 + (lane & 15);
        float v = acc[m][n][j] + brow[col] + addvec[col];
        v = fminf(fmaxf(v, -CLAMPV), CLAMPV);
        out[(size_t)row * DD + col] = v;
      }
    }
  }
}

extern "C" void kernel_launch(void* const* d_in, const int* in_sizes, int n_in,
                              void* d_out, int out_size, void* d_ws, size_t ws_size,
                              hipStream_t stream) {
  const float* codebook   = (const float*)d_in[0];
  const int*   base_idx   = (const int*)d_in[1];
  const int*   ref_idx    = (const int*)d_in[2];
  const float* transform  = (const float*)d_in[3];
  const float* contrib_w  = (const float*)d_in[4];
  const float* base_phase = (const float*)d_in[5];
  const float* amp        = (const float*)d_in[6];
  const float* freq       = (const float*)d_in[7];
  const float* poff       = (const float*)d_in[8];
  const float* err        = (const float*)d_in[9];
  const int*   tstep      = (const int*)d_in[10];
  float* out = (float*)d_out;

  // ws layout: [0,2048) addvec f32[512]; [2048, 2048+4MB) B fragment-image bf16
  float* addvec = (float*)d_ws;
  unsigned short* bt = (unsigned short*)((char*)d_ws + 2048);

  prep_phase_k<<<1, 512, 0, stream>>>(base_phase, amp, freq, poff, err, tstep, addvec);
  prep_bt_k<<<1024, 256, 0, stream>>>(transform, contrib_w, bt);
  rw_gemm_k<<<512, 512, 0, stream>>>(codebook, base_idx, ref_idx, bt, addvec, out);
}

// Round 6
// 320.094 us; speedup vs baseline: 2.7162x; 2.7162x over previous
//
#include <hip/hip_runtime.h>
#include <hip/hip_bf16.h>

// Problem constants
#define VV 200000
#define DD 512
#define NN 32768
#define RR 8
#define HH 16
#define CLAMPV 1000.0f

typedef __attribute__((ext_vector_type(8))) short short8;
typedef __attribute__((ext_vector_type(4))) float f32x4;
typedef __attribute__((ext_vector_type(4))) unsigned int u32x4;

__device__ __forceinline__ unsigned f2bf(float f) {
  union { float f; unsigned u; } v; v.f = f;
  return (v.u + 0x7FFFu + ((v.u >> 16) & 1u)) >> 16;   // RNE f32->bf16
}
__device__ __forceinline__ unsigned pack2(float lo, float hi) {
  return f2bf(lo) | (f2bf(hi) << 16);
}

// ---------------- prep 1: addvec[d] = clip(phase(t))[d] + err[d] -------------
__global__ void prep_phase_k(const float* __restrict__ base_phase,
                             const float* __restrict__ amp,
                             const float* __restrict__ freq,
                             const float* __restrict__ poff,
                             const float* __restrict__ err,
                             const int* __restrict__ tstep,
                             float* __restrict__ addvec) {
  const int d = threadIdx.x;          // 512 threads
  const float t = (float)(*tstep);
  float s = base_phase[d];
#pragma unroll
  for (int h = 0; h < HH; ++h)
    s += amp[h * DD + d] * sinf(freq[h] * t + poff[h]);
  s = fminf(fmaxf(s, -CLAMPV), CLAMPV);
  addvec[d] = s + err[d];
}

// ------------- prep 2: B in MFMA fragment-image layout -----------------------
// bt[((s*32 + g)*64 + l)*8 + j] = bf16( transform[k][e] * w[k/512] )
//   s = k32-slice (0..127), g = e-group (0..31), e = g*16 + (l&15),
//   k = s*32 + (l>>4)*8 + j  — the verified 16x16x32 B-fragment lane mapping.
__global__ void prep_bt_k(const float* __restrict__ transform,
                          const float* __restrict__ cw,
                          unsigned short* __restrict__ bt) {
  const int bid = blockIdx.x;                    // 1024 blocks x 256 threads
  const int s = bid >> 3;                        // 0..127
  const int g = ((bid & 7) << 2) + (threadIdx.x >> 6);  // 0..31
  const int l = threadIdx.x & 63;
  const int e = g * 16 + (l & 15);
  const int k0 = s * 32 + ((l >> 4) << 3);
  const float scale = cw[s >> 4];                // r = (s*32)/512, uniform
  u32x4 w;
#pragma unroll
  for (int p = 0; p < 4; ++p) {
    const float lo = transform[(size_t)(k0 + 2 * p) * DD + e] * scale;
    const float hi = transform[(size_t)(k0 + 2 * p + 1) * DD + e] * scale;
    w[p] = pack2(lo, hi);
  }
  *(u32x4*)(bt + (((size_t)s * 32 + g) * 64 + l) * 8) = w;
}

// ----------------------------- main fused GEMM -------------------------------
// C[32768x512] = gatherA[32768x4096] x B[4096x512] (+ base + addvec, clamp).
// BM=128, BN=512, 256 blocks (1/CU), 8 waves, wave = 128x64 (8x4 frags).
// 2-kt SUPERSTEPS (BK=128): one barrier per 2 kts. A-gather granule 512B
// contiguous f32 per row (4 threads x 128B). Single A reg buffer (unified
// regs: 128 AGPR acc + ~125 VGPR <= 256). Uniform vmcnt(16) schedule:
// per superstep issue order [B(2s+1), A(s+2), B(2s+2)], each wait(16)
// retires exactly the oldest 8-load group. LDS tile [128 rows][256B],
// chunk ^= (row&15) swizzle -> bank-uniform b128 reads AND writes.
#define VM_WAIT(N) asm volatile("s_waitcnt vmcnt(" #N ")" ::: "memory")
#define LGKM0()    asm volatile("s_waitcnt lgkmcnt(0)" ::: "memory")
#define BARRIER()  __builtin_amdgcn_s_barrier()

#define LOADB(DST, KT)                                                        \
  {                                                                           \
    const unsigned short* b0_ =                                               \
        bt + (size_t)(KT) * 32768 + wv * 2048 + lane * 8;                     \
    _Pragma("unroll") for (int n = 0; n < 4; ++n) {                           \
      DST[n][0] = *(const short8*)(b0_ + n * 512);                            \
      DST[n][1] = *(const short8*)(b0_ + 16384 + n * 512);                    \
    }                                                                         \
  }

#define LOADA(SLC)                                                            \
  {                                                                           \
    const int ri_ = refs_lds[arow2 * 8 + (((SLC) * 2) >> 3)];                 \
    const float* as_ = codebook + (size_t)ri_ * DD +                          \
                       (((SLC) & 3) << 7) + aq * 32;                          \
    _Pragma("unroll") for (int j = 0; j < 8; ++j)                             \
      as[j] = *(const f32x4*)(as_ + 4 * j);                                   \
  }

#define WRA(NXTB)                                                             \
  {                                                                           \
    _Pragma("unroll") for (int j = 0; j < 4; ++j) {                           \
      u32x4 w_;                                                               \
      w_[0] = pack2(as[2*j][0], as[2*j][1]);                                  \
      w_[1] = pack2(as[2*j][2], as[2*j][3]);                                  \
      w_[2] = pack2(as[2*j+1][0], as[2*j+1][1]);                              \
      w_[3] = pack2(as[2*j+1][2], as[2*j+1][3]);                              \
      *(u32x4*)((NXTB) + arow2 * 256 + (((4*aq + j) ^ (arow2 & 15)) << 4)) = w_;\
    }                                                                         \
  }

#define MFMA_KT(BF, CURB, P01)                                                \
  {                                                                           \
    __builtin_amdgcn_s_setprio(1);                                            \
    _Pragma("unroll") for (int ks = 0; ks < 2; ++ks) {                        \
      _Pragma("unroll") for (int m = 0; m < 8; ++m) {                         \
        const short8 aFv = *(const short8*)((CURB) + m * 4096 + rlo256 +      \
            (((((P01) << 3) | (ks << 2)) ^ hx) << 4));                        \
        _Pragma("unroll") for (int n = 0; n < 4; ++n)                         \
          acc[m][n] = __builtin_amdgcn_mfma_f32_16x16x32_bf16(                \
              aFv, (BF)[n][ks], acc[m][n], 0, 0, 0);                          \
      }                                                                       \
    }                                                                         \
    __builtin_amdgcn_s_setprio(0);                                            \
  }

// steady superstep S (0..29): cur has A(S), as-regs hold A(S+1) in flight
#define GSS(S, CURB, NXTB)                                                    \
  {                                                                           \
    LOADB(bF1, 2*(S)+1);                                                      \
    VM_WAIT(16);            /* retire A(S+1) -> as regs valid */              \
    WRA(NXTB);                                                                \
    LOADA((S)+2);           /* refill as with A(S+2) */                       \
    VM_WAIT(16);            /* retire B(2S) -> bF0 valid */                   \
    MFMA_KT(bF0, CURB, 0);                                                    \
    LOADB(bF0, 2*(S)+2);                                                      \
    VM_WAIT(16);            /* retire B(2S+1) -> bF1 valid */                 \
    MFMA_KT(bF1, CURB, 1);                                                    \
    LGKM0(); BARRIER();                                                       \
  }

__global__ __launch_bounds__(512, 2)
void rw_gemm_k(const float* __restrict__ codebook,
               const int* __restrict__ base_idx,
               const int* __restrict__ ref_idx,
               const unsigned short* __restrict__ bt,
               const float* __restrict__ addvec,
               float* __restrict__ out) {
  __shared__ unsigned short aT[2][128 * 128];    // 32 KB x2: [128 rows][256B]
  __shared__ int refs_lds[1024];                 // 128 rows x 8 refs

  const int tid = threadIdx.x;
  const int lane = tid & 63;
  const int wv = tid >> 6;                       // 0..7 -> col block (64 cols)
  const int mb = blockIdx.x;                     // rows mb*128 .. +127

  const f32x4 zero = {0.f, 0.f, 0.f, 0.f};
  f32x4 acc[8][4];
#pragma unroll
  for (int m = 0; m < 8; ++m)
#pragma unroll
    for (int n = 0; n < 4; ++n)
      acc[m][n] = zero;

  // A staging map: row = tid/4 (0..127), quarter aq = tid&3 (32 floats each)
  const int arow2 = tid >> 2;
  const int aq = tid & 3;
  char* ab0 = (char*)&aT[0][0];
  char* ab1 = (char*)&aT[1][0];

  // fragment-read constants: row = m*16 + (lane&15); swizzle chunk ^ (row&15)
  const int rlo256 = (lane & 15) * 256;
  const int hx = (lane >> 4) ^ (lane & 15);

  short8 bF0[4][2], bF1[4][2];
  f32x4 as[8];

  // ---- prologue ----
  refs_lds[tid] = ref_idx[(size_t)mb * 1024 + tid];
  refs_lds[512 + tid] = ref_idx[(size_t)mb * 1024 + 512 + tid];
  __syncthreads();

  LOADA(0);                 // A(0) slice (kt 0-1)
  VM_WAIT(0);
  WRA(ab0);
  LOADA(1);                 // A(1) in flight (oldest group)
  LOADB(bF0, 0);            // B(0) in flight
  LGKM0(); BARRIER();
  // entering s=0: in-flight = [A(1) x8, B(0) x8]  (matches steady order)

  // ---- supersteps s = 0..29 steady, 30/31 tail ----
  for (int u = 0; u < 15; ++u) {
    GSS(2 * u,     ab0, ab1);
    GSS(2 * u + 1, ab1, ab0);
  }
  // s=30 (kt 60,61): no LOADA
  {
    LOADB(bF1, 61);
    VM_WAIT(16);            // retire A(31)
    WRA(ab1);
    VM_WAIT(8);             // retire B(60)
    MFMA_KT(bF0, ab0, 0);
    LOADB(bF0, 62);
    VM_WAIT(8);             // retire B(61)
    MFMA_KT(bF1, ab0, 1);
    LGKM0(); BARRIER();
  }
  // s=31 (kt 62,63): cur = ab1
  {
    LOADB(bF1, 63);
    VM_WAIT(8);             // retire B(62)
    MFMA_KT(bF0, ab1, 0);
    VM_WAIT(0);             // retire B(63)
    MFMA_KT(bF1, ab1, 1);
  }

  // epilogue: + base gather + addvec, clamp, store f32
  // C/D layout: col = lane&15, row = (lane>>4)*4 + reg
#pragma unroll
  for (int m = 0; m < 8; ++m) {
#pragma unroll
    for (int j = 0; j < 4; ++j) {
      const int row = mb * 128 + m * 16 + ((lane >> 4) << 2) + j;
      const int bi = base_idx[row];
      const float* brow = codebook + (size_t)bi * DD;
#pragma unroll
      for (int n = 0; n < 4; ++n) {
        const int col = wv * 64 + n * 16 + (lane & 15);
        float v = acc[m][n][j] + brow[col] + addvec[col];
        v = fminf(fmaxf(v, -CLAMPV), CLAMPV);
        out[(size_t)row * DD + col] = v;
      }
    }
  }
}

extern "C" void kernel_launch(void* const* d_in, const int* in_sizes, int n_in,
                              void* d_out, int out_size, void* d_ws, size_t ws_size,
                              hipStream_t stream) {
  const float* codebook   = (const float*)d_in[0];
  const int*   base_idx   = (const int*)d_in[1];
  const int*   ref_idx    = (const int*)d_in[2];
  const float* transform  = (const float*)d_in[3];
  const float* contrib_w  = (const float*)d_in[4];
  const float* base_phase = (const float*)d_in[5];
  const float* amp        = (const float*)d_in[6];
  const float* freq       = (const float*)d_in[7];
  const float* poff       = (const float*)d_in[8];
  const float* err        = (const float*)d_in[9];
  const int*   tstep      = (const int*)d_in[10];
  float* out = (float*)d_out;

  // ws layout: [0,2048) addvec f32[512]; [2048, 2048+4MB) B fragment-image bf16
  float* addvec = (float*)d_ws;
  unsigned short* bt = (unsigned short*)((char*)d_ws + 2048);

  prep_phase_k<<<1, 512, 0, stream>>>(base_phase, amp, freq, poff, err, tstep, addvec);
  prep_bt_k<<<1024, 256, 0, stream>>>(transform, contrib_w, bt);
  rw_gemm_k<<<256, 512, 0, stream>>>(codebook, base_idx, ref_idx, bt, addvec, out);
}

// Round 7
// 227.894 us; speedup vs baseline: 3.8151x; 1.4046x over previous
//
#include <hip/hip_runtime.h>
#include <hip/hip_bf16.h>

// Problem constants
#define VV 200000
#define DD 512
#define NN 32768
#define RR 8
#define HH 16
#define CLAMPV 1000.0f

typedef __attribute__((ext_vector_type(8))) short short8;
typedef __attribute__((ext_vector_type(4))) float f32x4;
typedef __attribute__((ext_vector_type(4))) unsigned int u32x4;

__device__ __forceinline__ unsigned f2bf(float f) {
  union { float f; unsigned u; } v; v.f = f;
  return (v.u + 0x7FFFu + ((v.u >> 16) & 1u)) >> 16;   // RNE f32->bf16
}
__device__ __forceinline__ unsigned pack2(float lo, float hi) {
  return f2bf(lo) | (f2bf(hi) << 16);
}

// ---------------- prep 1: addvec[d] = clip(phase(t))[d] + err[d] -------------
__global__ void prep_phase_k(const float* __restrict__ base_phase,
                             const float* __restrict__ amp,
                             const float* __restrict__ freq,
                             const float* __restrict__ poff,
                             const float* __restrict__ err,
                             const int* __restrict__ tstep,
                             float* __restrict__ addvec) {
  const int d = threadIdx.x;          // 512 threads
  const float t = (float)(*tstep);
  float s = base_phase[d];
#pragma unroll
  for (int h = 0; h < HH; ++h)
    s += amp[h * DD + d] * sinf(freq[h] * t + poff[h]);
  s = fminf(fmaxf(s, -CLAMPV), CLAMPV);
  addvec[d] = s + err[d];
}

// ------------- prep 2: B in MFMA fragment-image layout -----------------------
// bt[((s*32 + g)*64 + l)*8 + j] = bf16( transform[k][e] * w[k/512] )
//   s = k32-slice (0..127), g = e-group (0..31), e = g*16 + (l&15),
//   k = s*32 + (l>>4)*8 + j  — the verified 16x16x32 B-fragment lane mapping.
__global__ void prep_bt_k(const float* __restrict__ transform,
                          const float* __restrict__ cw,
                          unsigned short* __restrict__ bt) {
  const int bid = blockIdx.x;                    // 1024 blocks x 256 threads
  const int s = bid >> 3;                        // 0..127
  const int g = ((bid & 7) << 2) + (threadIdx.x >> 6);  // 0..31
  const int l = threadIdx.x & 63;
  const int e = g * 16 + (l & 15);
  const int k0 = s * 32 + ((l >> 4) << 3);
  const float scale = cw[s >> 4];                // r = (s*32)/512, uniform
  u32x4 w;
#pragma unroll
  for (int p = 0; p < 4; ++p) {
    const float lo = transform[(size_t)(k0 + 2 * p) * DD + e] * scale;
    const float hi = transform[(size_t)(k0 + 2 * p + 1) * DD + e] * scale;
    w[p] = pack2(lo, hi);
  }
  *(u32x4*)(bt + (((size_t)s * 32 + g) * 64 + l) * 8) = w;
}

// ----------------------------- main fused GEMM -------------------------------
// C[32768x512] = gatherA[32768x4096] x B[4096x512] (+ base + addvec, clamp).
// BM=64, BN=512, BK=64. 512 blocks = 2 independent blocks/CU (two barrier
// domains -> cross-block TLP), 8 waves, wave = 64x64 (4x4 frags, acc=64).
// Register diet for 4 waves/SIMD (<=128 unified regs/wave): SINGLE-buffered
// B frags (32) and A stage (8). R1/R3's proven zero-conflict LDS layout.
// Counted-vmcnt schedule per kt:
//   LOADB(kt) -> vmcnt(8) [retire A(kt+1)] -> WRA -> LDA(kt+2)
//   -> vmcnt(2) [retire B(kt)] -> MFMA -> lgkm0 + barrier.
#define VM_WAIT(N) asm volatile("s_waitcnt vmcnt(" #N ")" ::: "memory")
#define LGKM0()    asm volatile("s_waitcnt lgkmcnt(0)" ::: "memory")
#define BARRIER()  __builtin_amdgcn_s_barrier()

#define LOADB(DST, KT)                                                        \
  {                                                                           \
    const unsigned short* b0_ =                                               \
        bt + (size_t)(KT) * 32768 + wv * 2048 + lane * 8;                     \
    _Pragma("unroll") for (int n = 0; n < 4; ++n) {                           \
      DST[n][0] = *(const short8*)(b0_ + n * 512);                            \
      DST[n][1] = *(const short8*)(b0_ + 16384 + n * 512);                    \
    }                                                                         \
  }

// GSTEP: one kt. ABR = LDS buf holding A(kt); ABW = other buf (gets A(kt+1)).
#define GSTEP(KT, ABR, ABW, DOA, VMB, DOBAR)                                  \
  {                                                                           \
    LOADB(bF, KT);                                                            \
    VM_WAIT(8);               /* retire A(KT+1) into as; B stays in flight */ \
    if ((KT) < 63) {          /* convert + ds_write A(KT+1) -> ABW */         \
      u32x4 w_;                                                               \
      w_[0] = pack2(as[0][0], as[0][1]); w_[1] = pack2(as[0][2], as[0][3]);   \
      w_[2] = pack2(as[1][0], as[1][1]); w_[3] = pack2(as[1][2], as[1][3]);   \
      *(u32x4*)((ABW) + awb) = w_;                                            \
    }                                                                         \
    if (DOA) {                /* A(KT+2) -> as (regs now free) */             \
      const int kt2_ = (KT) + 2;                                              \
      if ((kt2_ & 7) == 0) ridx = refs_lds[arow * 8 + (kt2_ >> 3)];           \
      const float* asrc_ =                                                    \
          codebook + (size_t)ridx * DD + ((kt2_ & 7) << 6) + ac8 * 8;         \
      as[0] = *(const f32x4*)(asrc_);                                         \
      as[1] = *(const f32x4*)(asrc_ + 4);                                     \
    }                                                                         \
    VM_WAIT(VMB);             /* retire B(KT); A(KT+2) stays in flight */     \
    __builtin_amdgcn_s_setprio(1);                                            \
    _Pragma("unroll") for (int ks = 0; ks < 2; ++ks) {                        \
      _Pragma("unroll") for (int m = 0; m < 4; ++m) {                         \
        const short8 aFv = *(const short8*)((ABR) + m * 2048 + rbase +        \
                                            ((ks * 64 + koff) ^ rsw));        \
        _Pragma("unroll") for (int n = 0; n < 4; ++n)                         \
          acc[m][n] = __builtin_amdgcn_mfma_f32_16x16x32_bf16(                \
              aFv, bF[n][ks], acc[m][n], 0, 0, 0);                            \
      }                                                                       \
    }                                                                         \
    __builtin_amdgcn_s_setprio(0);                                            \
    if (DOBAR) { LGKM0(); BARRIER(); }                                        \
  }

__global__ __launch_bounds__(512, 4)
void rw_gemm_k(const float* __restrict__ codebook,
               const int* __restrict__ base_idx,
               const int* __restrict__ ref_idx,
               const unsigned short* __restrict__ bt,
               const float* __restrict__ addvec,
               float* __restrict__ out) {
  __shared__ unsigned short aT[2][64 * 64];      // 8 KB x2, swizzled [row][k]
  __shared__ int refs_lds[512];                  // 64 rows x 8 refs

  const int tid = threadIdx.x;
  const int lane = tid & 63;
  const int wv = tid >> 6;                       // 0..7 -> col block (64 cols)
  const int mb = blockIdx.x;                     // rows mb*64 .. +63

  const f32x4 zero = {0.f, 0.f, 0.f, 0.f};
  f32x4 acc[4][4];
#pragma unroll
  for (int m = 0; m < 4; ++m)
#pragma unroll
    for (int n = 0; n < 4; ++n)
      acc[m][n] = zero;

  // A staging map (R1 zero-conflict): row = tid/8, 8 floats at chunk tid%8
  const int arow = tid >> 3;
  const int ac8 = tid & 7;
  const int awb = arow * 128 + ((ac8 * 16) ^ ((arow & 7) << 4));
  char* ab0 = (char*)&aT[0][0];
  char* ab1 = (char*)&aT[1][0];

  // fragment-read constants (R1 zero-conflict): row = m*16 + (lane&15)
  const int rsw = (lane & 7) << 4;
  const int rbase = (lane & 15) * 128;
  const int koff = (lane >> 4) * 16;

  short8 bF[4][2];
  f32x4 as[2];

  // ---- prologue: refs -> LDS; A(0) -> ab0; A(1) in flight in `as` ----
  refs_lds[tid] = ref_idx[(size_t)mb * 512 + tid];   // coalesced 2KB
  __syncthreads();
  int ridx = refs_lds[arow * 8];

  {
    const float* a0s = codebook + (size_t)ridx * DD + ac8 * 8;
    as[0] = *(const f32x4*)(a0s);
    as[1] = *(const f32x4*)(a0s + 4);
    VM_WAIT(0);
    u32x4 w_;
    w_[0] = pack2(as[0][0], as[0][1]); w_[1] = pack2(as[0][2], as[0][3]);
    w_[2] = pack2(as[1][0], as[1][1]); w_[3] = pack2(as[1][2], as[1][3]);
    *(u32x4*)(ab0 + awb) = w_;
    const float* a1s = codebook + (size_t)ridx * DD + 64 + ac8 * 8;  // kt=1
    as[0] = *(const f32x4*)(a1s);
    as[1] = *(const f32x4*)(a1s + 4);
    LGKM0(); BARRIER();
  }
  // entering kt=0: in flight = [A(1): 2 loads]

  // ---- main loop: kt = 0..61 steady (unrolled x2 for buffer parity) ----
  for (int k2 = 0; k2 < 31; ++k2) {
    const int kt = k2 * 2;
    GSTEP(kt,     ab0, ab1, 1, 2, 1);
    GSTEP(kt + 1, ab1, ab0, 1, 2, 1);
  }
  // kt=62: A(63) arrives, no new A; kt=63: last compute, no barrier
  GSTEP(62, ab0, ab1, 0, 0, 1);
  GSTEP(63, ab1, ab0, 0, 0, 0);

  // epilogue: + base gather + addvec, clamp, store f32
  // C/D layout: col = lane&15, row = (lane>>4)*4 + reg
#pragma unroll
  for (int m = 0; m < 4; ++m) {
#pragma unroll
    for (int j = 0; j < 4; ++j) {
      const int row = mb * 64 + m * 16 + ((lane >> 4) << 2) + j;
      const int bi = base_idx[row];
      const float* brow = codebook + (size_t)bi * DD;
#pragma unroll
      for (int n = 0; n < 4; ++n) {
        const int col = wv * 64 + n * 16 + (lane & 15);
        float v = acc[m][n][j] + brow[col] + addvec[col];
        v = fminf(fmaxf(v, -CLAMPV), CLAMPV);
        out[(size_t)row * DD + col] = v;
      }
    }
  }
}

extern "C" void kernel_launch(void* const* d_in, const int* in_sizes, int n_in,
                              void* d_out, int out_size, void* d_ws, size_t ws_size,
                              hipStream_t stream) {
  const float* codebook   = (const float*)d_in[0];
  const int*   base_idx   = (const int*)d_in[1];
  const int*   ref_idx    = (const int*)d_in[2];
  const float* transform  = (const float*)d_in[3];
  const float* contrib_w  = (const float*)d_in[4];
  const float* base_phase = (const float*)d_in[5];
  const float* amp        = (const float*)d_in[6];
  const float* freq       = (const float*)d_in[7];
  const float* poff       = (const float*)d_in[8];
  const float* err        = (const float*)d_in[9];
  const int*   tstep      = (const int*)d_in[10];
  float* out = (float*)d_out;

  // ws layout: [0,2048) addvec f32[512]; [2048, 2048+4MB) B fragment-image bf16
  float* addvec = (float*)d_ws;
  unsigned short* bt = (unsigned short*)((char*)d_ws + 2048);

  prep_phase_k<<<1, 512, 0, stream>>>(base_phase, amp, freq, poff, err, tstep, addvec);
  prep_bt_k<<<1024, 256, 0, stream>>>(transform, contrib_w, bt);
  rw_gemm_k<<<512, 512, 0, stream>>>(codebook, base_idx, ref_idx, bt, addvec, out);
}

// Round 8
// 191.101 us; speedup vs baseline: 4.5496x; 1.1925x over previous
//
#include <hip/hip_runtime.h>
#include <hip/hip_bf16.h>

// Problem constants
#define VV 200000
#define DD 512
#define NN 32768
#define RR 8
#define HH 16
#define CLAMPV 1000.0f

typedef __attribute__((ext_vector_type(8))) short short8;
typedef __attribute__((ext_vector_type(4))) float f32x4;
typedef __attribute__((ext_vector_type(4))) unsigned int u32x4;
typedef __attribute__((ext_vector_type(2))) unsigned int u32x2;

__device__ __forceinline__ unsigned f2bf(float f) {
  union { float f; unsigned u; } v; v.f = f;
  return (v.u + 0x7FFFu + ((v.u >> 16) & 1u)) >> 16;   // RNE f32->bf16
}
__device__ __forceinline__ unsigned pack2(float lo, float hi) {
  return f2bf(lo) | (f2bf(hi) << 16);
}

// ---------------- prep 1: addvec[d] = clip(phase(t))[d] + err[d] -------------
__global__ void prep_phase_k(const float* __restrict__ base_phase,
                             const float* __restrict__ amp,
                             const float* __restrict__ freq,
                             const float* __restrict__ poff,
                             const float* __restrict__ err,
                             const int* __restrict__ tstep,
                             float* __restrict__ addvec) {
  const int d = threadIdx.x;          // 512 threads
  const float t = (float)(*tstep);
  float s = base_phase[d];
#pragma unroll
  for (int h = 0; h < HH; ++h)
    s += amp[h * DD + d] * sinf(freq[h] * t + poff[h]);
  s = fminf(fmaxf(s, -CLAMPV), CLAMPV);
  addvec[d] = s + err[d];
}

// ------------- prep 2: B in MFMA fragment-image layout -----------------------
// bt[((s*32 + g)*64 + l)*8 + j] = bf16( transform[k][e] * w[k/512] )
//   s = k32-slice (0..127), g = e-group (0..31), e = g*16 + (l&15),
//   k = s*32 + (l>>4)*8 + j  — the verified 16x16x32 B-fragment lane mapping.
__global__ void prep_bt_k(const float* __restrict__ transform,
                          const float* __restrict__ cw,
                          unsigned short* __restrict__ bt) {
  const int bid = blockIdx.x;                    // 1024 blocks x 256 threads
  const int s = bid >> 3;                        // 0..127
  const int g = ((bid & 7) << 2) + (threadIdx.x >> 6);  // 0..31
  const int l = threadIdx.x & 63;
  const int e = g * 16 + (l & 15);
  const int k0 = s * 32 + ((l >> 4) << 3);
  const float scale = cw[s >> 4];                // r = (s*32)/512, uniform
  u32x4 w;
#pragma unroll
  for (int p = 0; p < 4; ++p) {
    const float lo = transform[(size_t)(k0 + 2 * p) * DD + e] * scale;
    const float hi = transform[(size_t)(k0 + 2 * p + 1) * DD + e] * scale;
    w[p] = pack2(lo, hi);
  }
  *(u32x4*)(bt + (((size_t)s * 32 + g) * 64 + l) * 8) = w;
}

// ----------------------------- main fused GEMM -------------------------------
// C[32768x512] = gatherA[32768x4096] x B[4096x512] (+ base + addvec, clamp).
// R3's PROVEN pipeline (dbuf B-frags 1 kt ahead, A 2 kt ahead via reg dbuf,
// counted vmcnt, raw barrier per kt), ONE change: wave tile 64x32 -> 16 waves
// (block=1024) so regs fit 4 waves/SIMD (acc 32 + bF 2x16 + as 2x4 ~ 95).
// BM=64, BN=512, BK=64, 512 blocks. Steady vmcnt(5) retires B(kt)4 + A(kt+1)1.
#define VM_WAIT(N) asm volatile("s_waitcnt vmcnt(" #N ")" ::: "memory")
#define LGKM0()    asm volatile("s_waitcnt lgkmcnt(0)" ::: "memory")
#define BARRIER()  __builtin_amdgcn_s_barrier()

// wave covers cols wv*32: e-groups wv*2, wv*2+1. 4 loads per kt.
#define LOADB(DST, KT)                                                        \
  {                                                                           \
    const unsigned short* b0_ =                                               \
        bt + (size_t)(KT) * 32768 + wv * 1024 + lane * 8;                     \
    DST[0][0] = *(const short8*)(b0_);                                        \
    DST[1][0] = *(const short8*)(b0_ + 512);                                  \
    DST[0][1] = *(const short8*)(b0_ + 16384);                                \
    DST[1][1] = *(const short8*)(b0_ + 16896);                                \
  }

// GSTEP: one kt. ASC = A(kt+1) regs (in flight->retired here, written to ABW);
// ASN = free regs, gets A(kt+2) issue. BFC = B(kt) (retired here, consumed);
// BFN = gets B(kt+1) issue. ABR = LDS buf holding A(kt).
#define GSTEP(KT, ASC, ASN, BFC, BFN, ABR, ABW, VMN, DOA, DOB, DOBAR)         \
  {                                                                           \
    if (DOB) LOADB(BFN, (KT) + 1);                                            \
    if (DOA) { /* A(KT+2) -> ASN: 1 dwordx4/thread, 16 thr x 16B per row */   \
      const int kt2_ = (KT) + 2;                                              \
      if ((kt2_ & 7) == 0) ridx = refs_lds[arow * 8 + (kt2_ >> 3)];           \
      ASN = *(const f32x4*)(codebook + (size_t)ridx * DD +                    \
                            ((kt2_ & 7) << 6) + (ac << 2));                   \
    }                                                                         \
    VM_WAIT(VMN);             /* retire B(KT) + A(KT+1); newer in flight */   \
    if ((KT) < 63) {          /* convert + ds_write A(KT+1) -> ABW */         \
      u32x2 w_ = {pack2(ASC[0], ASC[1]), pack2(ASC[2], ASC[3])};              \
      *(u32x2*)((ABW) + awb) = w_;                                            \
    }                                                                         \
    __builtin_amdgcn_s_setprio(1);                                            \
    _Pragma("unroll") for (int ks = 0; ks < 2; ++ks) {                        \
      _Pragma("unroll") for (int m = 0; m < 4; ++m) {                         \
        const short8 aFv = *(const short8*)((ABR) + m * 2048 + rbase +        \
            ((((ks * 4 + koff4) ^ rsw7)) << 4));                              \
        _Pragma("unroll") for (int n = 0; n < 2; ++n)                         \
          acc[m][n] = __builtin_amdgcn_mfma_f32_16x16x32_bf16(                \
              aFv, (BFC)[n][ks], acc[m][n], 0, 0, 0);                         \
      }                                                                       \
    }                                                                         \
    __builtin_amdgcn_s_setprio(0);                                            \
    if (DOBAR) { LGKM0(); BARRIER(); }                                        \
  }

__global__ __launch_bounds__(1024, 4)
void rw_gemm_k(const float* __restrict__ codebook,
               const int* __restrict__ base_idx,
               const int* __restrict__ ref_idx,
               const unsigned short* __restrict__ bt,
               const float* __restrict__ addvec,
               float* __restrict__ out) {
  __shared__ unsigned short aT[2][64 * 64];      // 8 KB x2, swizzled [row][128B]
  __shared__ int refs_lds[512];                  // 64 rows x 8 refs

  const int tid = threadIdx.x;                   // 1024 threads = 16 waves
  const int lane = tid & 63;
  const int wv = tid >> 6;                       // 0..15 -> col block (32 cols)
  const int mb = blockIdx.x;                     // rows mb*64 .. +63

  const f32x4 zero = {0.f, 0.f, 0.f, 0.f};
  f32x4 acc[4][2];
#pragma unroll
  for (int m = 0; m < 4; ++m)
#pragma unroll
    for (int n = 0; n < 2; ++n)
      acc[m][n] = zero;

  // A staging map: row = tid/16 (0..63), 4 floats at f32-chunk ac = tid&15
  const int arow = tid >> 4;
  const int ac = tid & 15;
  // write 8B at row*128 + swizzled 16B-chunk (ac>>1)^(row&7), half ac&1
  const int awb = arow * 128 + ((((ac >> 1) ^ (arow & 7)) << 4) | ((ac & 1) << 3));
  char* ab0 = (char*)&aT[0][0];
  char* ab1 = (char*)&aT[1][0];

  // fragment-read constants: row = m*16 + (lane&15); chunk = ks*4 + (lane>>4)
  const int rsw7 = lane & 7;
  const int rbase = (lane & 15) * 128;
  const int koff4 = lane >> 4;

  short8 bF0[2][2], bF1[2][2];
  f32x4 as0, as1;

  // ---- prologue: refs -> LDS; A(0)->ab0; [B(0):4, A(1):1] left in flight ----
  if (tid < 512) refs_lds[tid] = ref_idx[(size_t)mb * 512 + tid];
  __syncthreads();
  int ridx = refs_lds[arow * 8];

  as0 = *(const f32x4*)(codebook + (size_t)ridx * DD + (ac << 2));   // A(0)
  VM_WAIT(0);
  {
    u32x2 w_ = {pack2(as0[0], as0[1]), pack2(as0[2], as0[3])};
    *(u32x2*)(ab0 + awb) = w_;
  }
  LOADB(bF0, 0);                                               // B(0): 4 loads
  as1 = *(const f32x4*)(codebook + (size_t)ridx * DD + 64 + (ac << 2)); // A(1)
  LGKM0(); BARRIER();

  // ---- main loop: kt = 0..61 steady, 62/63 tail ----
  for (int k2 = 0; k2 < 31; ++k2) {
    const int kt = k2 * 2;
    GSTEP(kt,     as1, as0, bF0, bF1, ab0, ab1, 5, 1, 1, 1);
    GSTEP(kt + 1, as0, as1, bF1, bF0, ab1, ab0, 5, 1, 1, 1);
  }
  GSTEP(62, as1, as0, bF0, bF1, ab0, ab1, 4, 0, 1, 1);
  GSTEP(63, as0, as1, bF1, bF0, ab1, ab0, 0, 0, 0, 0);

  // epilogue: + base gather + addvec, clamp, store f32
  // C/D layout: col = lane&15, row = (lane>>4)*4 + reg
#pragma unroll
  for (int m = 0; m < 4; ++m) {
#pragma unroll
    for (int j = 0; j < 4; ++j) {
      const int row = mb * 64 + m * 16 + ((lane >> 4) << 2) + j;
      const int bi = base_idx[row];
      const float* brow = codebook + (size_t)bi * DD;
#pragma unroll
      for (int n = 0; n < 2; ++n) {
        const int col = wv * 32 + n * 16 + (lane & 15);
        float v = acc[m][n][j] + brow[col] + addvec[col];
        v = fminf(fmaxf(v, -CLAMPV), CLAMPV);
        out[(size_t)row * DD + col] = v;
      }
    }
  }
}

extern "C" void kernel_launch(void* const* d_in, const int* in_sizes, int n_in,
                              void* d_out, int out_size, void* d_ws, size_t ws_size,
                              hipStream_t stream) {
  const float* codebook   = (const float*)d_in[0];
  const int*   base_idx   = (const int*)d_in[1];
  const int*   ref_idx    = (const int*)d_in[2];
  const float* transform  = (const float*)d_in[3];
  const float* contrib_w  = (const float*)d_in[4];
  const float* base_phase = (const float*)d_in[5];
  const float* amp        = (const float*)d_in[6];
  const float* freq       = (const float*)d_in[7];
  const float* poff       = (const float*)d_in[8];
  const float* err        = (const float*)d_in[9];
  const int*   tstep      = (const int*)d_in[10];
  float* out = (float*)d_out;

  // ws layout: [0,2048) addvec f32[512]; [2048, 2048+4MB) B fragment-image bf16
  float* addvec = (float*)d_ws;
  unsigned short* bt = (unsigned short*)((char*)d_ws + 2048);

  prep_phase_k<<<1, 512, 0, stream>>>(base_phase, amp, freq, poff, err, tstep, addvec);
  prep_bt_k<<<1024, 256, 0, stream>>>(transform, contrib_w, bt);
  rw_gemm_k<<<512, 1024, 0, stream>>>(codebook, base_idx, ref_idx, bt, addvec, out);
}

// Round 9
// 183.323 us; speedup vs baseline: 4.7426x; 1.0424x over previous
//
#include <hip/hip_runtime.h>
#include <hip/hip_bf16.h>

// Problem constants
#define VV 200000
#define DD 512
#define NN 32768
#define RR 8
#define HH 16
#define CLAMPV 1000.0f

typedef __attribute__((ext_vector_type(8))) short short8;
typedef __attribute__((ext_vector_type(4))) float f32x4;
typedef __attribute__((ext_vector_type(4))) unsigned int u32x4;

__device__ __forceinline__ unsigned f2bf(float f) {
  union { float f; unsigned u; } v; v.f = f;
  return (v.u + 0x7FFFu + ((v.u >> 16) & 1u)) >> 16;   // RNE f32->bf16
}
__device__ __forceinline__ unsigned pack2(float lo, float hi) {
  return f2bf(lo) | (f2bf(hi) << 16);
}

// ---------------- prep 1: addvec[d] = clip(phase(t))[d] + err[d] -------------
__global__ void prep_phase_k(const float* __restrict__ base_phase,
                             const float* __restrict__ amp,
                             const float* __restrict__ freq,
                             const float* __restrict__ poff,
                             const float* __restrict__ err,
                             const int* __restrict__ tstep,
                             float* __restrict__ addvec) {
  const int d = threadIdx.x;          // 512 threads
  const float t = (float)(*tstep);
  float s = base_phase[d];
#pragma unroll
  for (int h = 0; h < HH; ++h)
    s += amp[h * DD + d] * sinf(freq[h] * t + poff[h]);
  s = fminf(fmaxf(s, -CLAMPV), CLAMPV);
  addvec[d] = s + err[d];
}

// ------------- prep 2: B in MFMA fragment-image layout -----------------------
// bt[((s*32 + g)*64 + l)*8 + j] = bf16( transform[k][e] * w[k/512] )
//   s = k32-slice (0..127), g = e-group (0..31), e = g*16 + (l&15),
//   k = s*32 + (l>>4)*8 + j  — the verified 16x16x32 B-fragment lane mapping.
__global__ void prep_bt_k(const float* __restrict__ transform,
                          const float* __restrict__ cw,
                          unsigned short* __restrict__ bt) {
  const int bid = blockIdx.x;                    // 1024 blocks x 256 threads
  const int s = bid >> 3;                        // 0..127
  const int g = ((bid & 7) << 2) + (threadIdx.x >> 6);  // 0..31
  const int l = threadIdx.x & 63;
  const int e = g * 16 + (l & 15);
  const int k0 = s * 32 + ((l >> 4) << 3);
  const float scale = cw[s >> 4];                // r = (s*32)/512, uniform
  u32x4 w;
#pragma unroll
  for (int p = 0; p < 4; ++p) {
    const float lo = transform[(size_t)(k0 + 2 * p) * DD + e] * scale;
    const float hi = transform[(size_t)(k0 + 2 * p + 1) * DD + e] * scale;
    w[p] = pack2(lo, hi);
  }
  *(u32x4*)(bt + (((size_t)s * 32 + g) * 64 + l) * 8) = w;
}

// ----------------------------- main fused GEMM -------------------------------
// C[32768x512] = gatherA[32768x4096] x B[4096x512] (+ base + addvec, clamp).
// PRODUCER-CONSUMER wave specialization. BM=64, BN=512, BK=64, 512 blocks.
// Block = 12 waves: waves 0-7 CONSUMERS (64x64 tile each, acc 4x4, B-frag reg
// dbuf from L2-resident fragment-image ws), waves 8-11 PRODUCERS (gather
// codebook rows f32 -> bf16 -> 4-deep LDS ring, 4 static reg-sets, running
// 4 kts ahead; vmcnt(8) waits on loads issued 2 kts (~4000 cyc) earlier).
// One s_barrier per kt; both roles execute exactly 64 barriers.
// Ring slots use R1's PROVEN zero-conflict layout: row*128B, 16B-chunk
// XOR (row&7) — identical swizzle on producer writes and consumer reads.
#define VM_WAIT(N) asm volatile("s_waitcnt vmcnt(" #N ")" ::: "memory")
#define LGKM0()    asm volatile("s_waitcnt lgkmcnt(0)" ::: "memory")
#define BARRIER()  __builtin_amdgcn_s_barrier()

#define LOADB(DST, KT)                                                        \
  {                                                                           \
    const unsigned short* b0_ =                                               \
        bt + (size_t)(KT) * 32768 + wv * 2048 + lane * 8;                     \
    _Pragma("unroll") for (int n = 0; n < 4; ++n) {                           \
      DST[n][0] = *(const short8*)(b0_ + n * 512);                            \
      DST[n][1] = *(const short8*)(b0_ + 16384 + n * 512);                    \
    }                                                                         \
  }

#define CMFMA(BF, SLOT)                                                       \
  {                                                                           \
    char* ab_ = (char*)&ring[SLOT][0];                                        \
    __builtin_amdgcn_s_setprio(1);                                            \
    _Pragma("unroll") for (int ks = 0; ks < 2; ++ks) {                        \
      _Pragma("unroll") for (int m = 0; m < 4; ++m) {                         \
        const short8 aFv = *(const short8*)(ab_ + m * 2048 + rbase +          \
                                            ((ks * 64 + koff) ^ rsw));        \
        _Pragma("unroll") for (int n = 0; n < 4; ++n)                         \
          acc[m][n] = __builtin_amdgcn_mfma_f32_16x16x32_bf16(                \
              aFv, (BF)[n][ks], acc[m][n], 0, 0, 0);                          \
      }                                                                       \
    }                                                                         \
    __builtin_amdgcn_s_setprio(0);                                            \
  }

// producer: load 16 floats (64B contiguous) of row `prow`, k-slice KT
#define PLOAD(SET, KT)                                                        \
  {                                                                           \
    const int ri_ = refs_lds[prow8 + ((KT) >> 3)];                            \
    const float* s_ = codebook + (size_t)ri_ * DD + (((KT) & 7) << 6) + pq16; \
    SET[0] = *(const f32x4*)(s_);                                             \
    SET[1] = *(const f32x4*)(s_ + 4);                                         \
    SET[2] = *(const f32x4*)(s_ + 8);                                         \
    SET[3] = *(const f32x4*)(s_ + 12);                                        \
  }

#define PWRITE(SET, SLOT)                                                     \
  {                                                                           \
    char* d_ = (char*)&ring[SLOT][0];                                         \
    u32x4 wa_, wb_;                                                           \
    wa_[0] = pack2(SET[0][0], SET[0][1]); wa_[1] = pack2(SET[0][2], SET[0][3]);\
    wa_[2] = pack2(SET[1][0], SET[1][1]); wa_[3] = pack2(SET[1][2], SET[1][3]);\
    wb_[0] = pack2(SET[2][0], SET[2][1]); wb_[1] = pack2(SET[2][2], SET[2][3]);\
    wb_[2] = pack2(SET[3][0], SET[3][1]); wb_[3] = pack2(SET[3][2], SET[3][3]);\
    *(u32x4*)(d_ + wb0) = wa_;                                                \
    *(u32x4*)(d_ + wb1) = wb_;                                                \
  }

__global__ __launch_bounds__(768, 3)
void rw_gemm_k(const float* __restrict__ codebook,
               const int* __restrict__ base_idx,
               const int* __restrict__ ref_idx,
               const unsigned short* __restrict__ bt,
               const float* __restrict__ addvec,
               float* __restrict__ out) {
  __shared__ unsigned short ring[4][64 * 64];    // 4 slots x 8 KB
  __shared__ int refs_lds[512];                  // 64 rows x 8 refs

  const int tid = threadIdx.x;                   // 768 threads = 12 waves
  const int lane = tid & 63;
  const int wv = tid >> 6;                       // 0..7 consumers, 8..11 prod
  const int mb = blockIdx.x;                     // rows mb*64 .. +63

  if (tid < 512) refs_lds[tid] = ref_idx[(size_t)mb * 512 + tid];
  __syncthreads();

  if (wv < 8) {
    // =========================== CONSUMER ===========================
    const f32x4 zero = {0.f, 0.f, 0.f, 0.f};
    f32x4 acc[4][4];
#pragma unroll
    for (int m = 0; m < 4; ++m)
#pragma unroll
      for (int n = 0; n < 4; ++n)
        acc[m][n] = zero;

    // fragment-read constants (R1 zero-conflict): row = m*16 + (lane&15)
    const int rsw = (lane & 7) << 4;
    const int rbase = (lane & 15) * 128;
    const int koff = (lane >> 4) * 16;

    short8 bF0[4][2], bF1[4][2];

    LOADB(bF0, 0);            // B(0) in flight (8 loads)
    BARRIER();                // matches producer prologue barrier

    // kt = 0..61 (unroll 2 for bF parity), 62, 63
    for (int k2 = 0; k2 < 31; ++k2) {
      const int kt = k2 * 2;
      LOADB(bF1, kt + 1);
      VM_WAIT(8);             // retire B(kt)
      CMFMA(bF0, (kt & 3));
      LGKM0(); BARRIER();
      LOADB(bF0, kt + 2);
      VM_WAIT(8);             // retire B(kt+1)
      CMFMA(bF1, ((kt + 1) & 3));
      LGKM0(); BARRIER();
    }
    LOADB(bF1, 63);
    VM_WAIT(8);
    CMFMA(bF0, 2);            // kt=62
    LGKM0(); BARRIER();
    VM_WAIT(0);
    CMFMA(bF1, 3);            // kt=63 (no barrier)

    // epilogue: + base gather + addvec, clamp, store f32
    // C/D layout: col = lane&15, row = (lane>>4)*4 + reg
#pragma unroll
    for (int m = 0; m < 4; ++m) {
#pragma unroll
      for (int j = 0; j < 4; ++j) {
        const int row = mb * 64 + m * 16 + ((lane >> 4) << 2) + j;
        const int bi = base_idx[row];
        const float* brow = codebook + (size_t)bi * DD;
#pragma unroll
        for (int n = 0; n < 4; ++n) {
          const int col = wv * 64 + n * 16 + (lane & 15);
          float v = acc[m][n][j] + brow[col] + addvec[col];
          v = fminf(fmaxf(v, -CLAMPV), CLAMPV);
          out[(size_t)row * DD + col] = v;
        }
      }
    }
  } else {
    // =========================== PRODUCER ===========================
    const int p = tid - 512;                     // 0..255
    const int prow = p >> 2;                     // 0..63: owned row
    const int pq16 = (p & 3) << 4;               // 16-float segment
    const int prow8 = prow * 8;
    const int sw = prow & 7;
    const int wb0 = prow * 128 + ((((p & 3) * 2) ^ sw) << 4);
    const int wb1 = prow * 128 + ((((p & 3) * 2 + 1) ^ sw) << 4);

    f32x4 s0[4], s1[4], s2[4], s3[4];

    // prologue: L(0..3) in flight; write slots 0,1; leave L2,L3 in flight
    PLOAD(s0, 0); PLOAD(s1, 1); PLOAD(s2, 2); PLOAD(s3, 3);
    VM_WAIT(12); PWRITE(s0, 0);
    VM_WAIT(8);  PWRITE(s1, 1);
    LGKM0(); BARRIER();

    // steady: kt = 0..59 — issue L(kt+4), retire L(kt+2), write slot (kt+2)&3
    for (int u = 0; u < 15; ++u) {
      const int kt = u * 4;
      PLOAD(s0, kt + 4); VM_WAIT(8); PWRITE(s2, 2); LGKM0(); BARRIER();
      PLOAD(s1, kt + 5); VM_WAIT(8); PWRITE(s3, 3); LGKM0(); BARRIER();
      PLOAD(s2, kt + 6); VM_WAIT(8); PWRITE(s0, 0); LGKM0(); BARRIER();
      PLOAD(s3, kt + 7); VM_WAIT(8); PWRITE(s1, 1); LGKM0(); BARRIER();
    }
    // kt=60: retire L(62), write slot 2
    VM_WAIT(4); PWRITE(s2, 2); LGKM0(); BARRIER();
    // kt=61: retire L(63), write slot 3
    VM_WAIT(0); PWRITE(s3, 3); LGKM0(); BARRIER();
    // kt=62: idle step (consumers compute kt=62)
    BARRIER();
    // kt=63: no barrier; done
  }
}

extern "C" void kernel_launch(void* const* d_in, const int* in_sizes, int n_in,
                              void* d_out, int out_size, void* d_ws, size_t ws_size,
                              hipStream_t stream) {
  const float* codebook   = (const float*)d_in[0];
  const int*   base_idx   = (const int*)d_in[1];
  const int*   ref_idx    = (const int*)d_in[2];
  const float* transform  = (const float*)d_in[3];
  const float* contrib_w  = (const float*)d_in[4];
  const float* base_phase = (const float*)d_in[5];
  const float* amp        = (const float*)d_in[6];
  const float* freq       = (const float*)d_in[7];
  const float* poff       = (const float*)d_in[8];
  const float* err        = (const float*)d_in[9];
  const int*   tstep      = (const int*)d_in[10];
  float* out = (float*)d_out;

  // ws layout: [0,2048) addvec f32[512]; [2048, 2048+4MB) B fragment-image bf16
  float* addvec = (float*)d_ws;
  unsigned short* bt = (unsigned short*)((char*)d_ws + 2048);

  prep_phase_k<<<1, 512, 0, stream>>>(base_phase, amp, freq, poff, err, tstep, addvec);
  prep_bt_k<<<1024, 256, 0, stream>>>(transform, contrib_w, bt);
  rw_gemm_k<<<512, 768, 0, stream>>>(codebook, base_idx, ref_idx, bt, addvec, out);
}